// Round 6
// baseline (136.936 us; speedup 1.0000x reference)
//
#include <hip/hip_runtime.h>
#include <stdint.h>

// BlockAttention: B=8, S=8192, D=H=128, BLOCK=256, WINDOW=256 (halo 255, W=766)
// No softmax => out_blk = Q_blk @ (scale * M_n),  M_n^T[h][d] = sum over window
// keys of v[h]*k[d], window = halves [2n-2, 2n+3] clipped, minus key a=(n-1)*256
// (col 0 of half 2n-2) and key z=(n+1)*256+255 (col 127 of half 2n+3) -- both
// handled by ZEROING those K^T tile columns (no rank-1 fixups).
// SINGLE kernel, 256 blocks (b,n) x 512 thr (8 waves), no workspace:
//   Q proj -> q_l -> qf regs;  loop over 6 halves: {K/V proj from LDS-resident
//   weights, transpose->tiles (edge-zeroed), C-GEMM accumulate in macc regs};
//   M^T -> m_l bf16;  O = Q*M;  epilogue.
// XCD swizzle: consecutive (b,n) cluster per XCD so halo x re-reads hit L2.

#define B_ 8
#define S_ 8192
#define LDW 136   // padded leading dim (shorts), 16B-aligned rows
#define LDH 136   // half-tile leading dim (shorts)

using bf16x8 = __attribute__((ext_vector_type(8))) short;   // 8 bf16 = 4 VGPRs
using s16x4  = __attribute__((ext_vector_type(4))) short;
using f32x16 = __attribute__((ext_vector_type(16))) float;

__device__ __forceinline__ short f2bf(float f) {
  union { float f; uint32_t u; } v; v.f = f;
  uint32_t r = v.u + 0x7fffu + ((v.u >> 16) & 1u);   // RNE
  return (short)(r >> 16);
}

// LDS map (139,264 B):
//  area1 [0,34816):        Wq stage -> Wk stage (resident through loop)
//  area2 [34816,69632):    Wv stage (resident) -> m_l [128][LDW] after loop
//  ktile [69632,104448):   K^T half tile [128][LDH]
//  vtile [104448,139264):  V^T half tile [128][LDH]
//  q_l   [69632,139264):   Q tile [256][LDW] (before loop; dies at 1st barrier)
//  opat  [69632,106496):   epilogue patches 8*32*36 f32 (after loop)
__global__ __launch_bounds__(512) void fused_kernel(
    const float* __restrict__ x,
    const float* __restrict__ Wq, const float* __restrict__ bq,
    const float* __restrict__ Wk, const float* __restrict__ bk,
    const float* __restrict__ Wv, const float* __restrict__ bv,
    float* __restrict__ out)
{
  __shared__ __align__(16) char smem[139264];
  short* area1 = (short*)smem;
  short* area2 = (short*)(smem + 34816);
  short* ktile = (short*)(smem + 69632);
  short* vtile = (short*)(smem + 104448);
  short* q_l   = (short*)(smem + 69632);
  short* m_l   = (short*)(smem + 34816);
  float* opat  = (float*)(smem + 69632);

  const int tid  = threadIdx.x;
  const int lane = tid & 63;
  const int wv   = tid >> 6;        // 0..7
  const int c    = lane & 31;
  const int hl   = lane >> 5;
  // bijective XCD swizzle (256 % 8 == 0): XCD k owns contiguous wg ids k*32..+32
  const int wg   = ((int)blockIdx.x & 7) * 32 + ((int)blockIdx.x >> 3);
  const int r0   = wg * 256;
  const int b    = r0 >> 13;
  const int n    = (r0 & (S_ - 1)) >> 8;
  const int rg   = wv >> 1;         // half-proj row-group / C-GEMM h-group
  const int dh   = wv & 1;          // half-proj col-half / C-GEMM d-half

  // load 8 A-frags for 32 rows starting at global row `row0` (lanes add c)
  auto loadA = [&](bf16x8* af, int row0) {
    const float* xr = x + ((size_t)row0 + c) * 128 + hl * 8;
    #pragma unroll
    for (int kst = 0; kst < 8; ++kst) {
      const float4* p = (const float4*)(xr + kst * 16);
      float4 f0 = p[0], f1 = p[1];
      bf16x8 a;
      a[0] = f2bf(f0.x); a[1] = f2bf(f0.y); a[2] = f2bf(f0.z); a[3] = f2bf(f0.w);
      a[4] = f2bf(f1.x); a[5] = f2bf(f1.y); a[6] = f2bf(f1.z); a[7] = f2bf(f1.w);
      af[kst] = a;
    }
  };

  auto stageW = [&](const float* W, short* wl) {   // 128x128 f32 -> bf16
    #pragma unroll
    for (int it = 0; it < 8; ++it) {
      int l  = it * 512 + tid;
      int nn = l >> 5;
      int k4 = (l & 31) << 2;
      const float4 f = *(const float4*)(W + nn * 128 + k4);
      s16x4 o;
      o[0] = f2bf(f.x); o[1] = f2bf(f.y); o[2] = f2bf(f.z); o[3] = f2bf(f.w);
      *(s16x4*)(wl + nn * LDW + k4) = o;
    }
  };

  // half projection: wave computes rows rg*32..+32, cols (2dh+t)*32..+32
  auto projHalf = [&](const float* bias, f32x16* acc, const short* wl,
                      const bf16x8* af) {
    #pragma unroll
    for (int t = 0; t < 2; ++t) {
      float bvv = bias[(2 * dh + t) * 32 + c];
      #pragma unroll
      for (int i = 0; i < 16; ++i) acc[t][i] = bvv;
    }
    #pragma unroll
    for (int kst = 0; kst < 8; ++kst) {
      #pragma unroll
      for (int t = 0; t < 2; ++t) {
        bf16x8 bb = *(const bf16x8*)(wl + ((2 * dh + t) * 32 + c) * LDW +
                                     kst * 16 + hl * 8);
        acc[t] = __builtin_amdgcn_mfma_f32_32x32x16_bf16(af[kst], bb, acc[t], 0, 0, 0);
      }
    }
  };

  // acc (rows = half keys s, cols = d/h) -> tile[d][s], optional edge-zeroing
  auto transpHalf = [&](f32x16* acc, short* tile, bool eL, bool eR) {
    #pragma unroll
    for (int t = 0; t < 2; ++t) {
      int d = (2 * dh + t) * 32 + c;
      #pragma unroll
      for (int g = 0; g < 4; ++g) {
        #pragma unroll
        for (int p = 0; p < 2; ++p) {
          int reg = g * 4 + p * 2;
          int sl  = rg * 32 + g * 8 + hl * 4 + p * 2;   // 0..126 even
          uint32_t pk = (uint32_t)(uint16_t)f2bf(acc[t][reg]) |
                        ((uint32_t)(uint16_t)f2bf(acc[t][reg + 1]) << 16);
          if (eL && sl == 0)   pk &= 0xFFFF0000u;   // zero col 0   (key a)
          if (eR && sl == 126) pk &= 0x0000FFFFu;   // zero col 127 (key z)
          *(uint32_t*)(tile + d * LDH + sl) = pk;
        }
      }
    }
  };

  // C^T[h][d] += sum_s V^T[h][s] * K^T[d][s] over this half (s=0..127)
  auto cgemm = [&](f32x16* mc) {
    #pragma unroll
    for (int kst = 0; kst < 8; ++kst) {
      bf16x8 a = *(const bf16x8*)(vtile + (rg * 32 + c) * LDH + kst * 16 + hl * 8);
      #pragma unroll
      for (int t = 0; t < 2; ++t) {
        bf16x8 bb = *(const bf16x8*)(ktile + (dh * 64 + t * 32 + c) * LDH +
                                     kst * 16 + hl * 8);
        mc[t] = __builtin_amdgcn_mfma_f32_32x32x16_bf16(a, bb, mc[t], 0, 0, 0);
      }
    }
  };

  // ---------------- Q phase ----------------
  bf16x8 afA[8];
  loadA(afA, r0 + wv * 32);          // own Q rows for this wave
  stageW(Wq, area1);
  __syncthreads();

  f32x16 qacc[4];
  {
    #pragma unroll
    for (int nt = 0; nt < 4; ++nt) {
      float bvv = bq[nt * 32 + c];
      #pragma unroll
      for (int i = 0; i < 16; ++i) qacc[nt][i] = bvv;
    }
    #pragma unroll
    for (int kst = 0; kst < 8; ++kst) {
      #pragma unroll
      for (int nt = 0; nt < 4; ++nt) {
        bf16x8 bb = *(const bf16x8*)(area1 + (nt * 32 + c) * LDW + kst * 16 + hl * 8);
        qacc[nt] = __builtin_amdgcn_mfma_f32_32x32x16_bf16(afA[kst], bb, qacc[nt], 0, 0, 0);
      }
    }
  }
  __syncthreads();                   // Wq reads done -> area1 reusable

  // Q transpose -> q_l [s][d] (wave-local rows wv*32..+32)
  #pragma unroll
  for (int nt = 0; nt < 4; ++nt) {
    #pragma unroll
    for (int reg = 0; reg < 16; ++reg) {
      int row = (reg & 3) + 8 * (reg >> 2) + 4 * hl;
      q_l[(wv * 32 + row) * LDW + nt * 32 + c] = f2bf(qacc[nt][reg]);
    }
  }
  stageW(Wk, area1);
  stageW(Wv, area2);
  const int jlo = (n == 0) ? 0 : 2 * n - 2;
  const int jhi = (n == 31) ? 64 : 2 * n + 4;
  loadA(afA, b * S_ + jlo * 128 + rg * 32);   // prefetch first half
  __syncthreads();                   // q_l + weights visible

  bf16x8 qf[8];
  #pragma unroll
  for (int kst = 0; kst < 8; ++kst)
    qf[kst] = *(const bf16x8*)(q_l + (wv * 32 + c) * LDW + kst * 16 + hl * 8);

  // ---------------- window loop (pairs of halves) ----------------
  f32x16 macc[2];
  #pragma unroll
  for (int t = 0; t < 2; ++t)
    #pragma unroll
    for (int i = 0; i < 16; ++i) macc[t][i] = 0.f;

  for (int jj = jlo; jj < jhi; jj += 2) {
    bf16x8 afB[8];
    loadA(afB, b * S_ + (jj + 1) * 128 + rg * 32);
    {
      f32x16 ka[2];
      projHalf(bk, ka, area1, afA);
      __syncthreads();               // prev C-GEMM tile reads done (+ qf reads)
      transpHalf(ka, ktile, jj == 2 * n - 2, false);   // even half: only eL
    }
    {
      f32x16 va[2];
      projHalf(bv, va, area2, afA);
      transpHalf(va, vtile, false, false);
    }
    __syncthreads();
    cgemm(macc);
    if (jj + 2 < jhi) loadA(afA, b * S_ + (jj + 2) * 128 + rg * 32);
    {
      f32x16 kb[2];
      projHalf(bk, kb, area1, afB);
      __syncthreads();               // C-GEMM tile reads done
      transpHalf(kb, ktile, false, jj + 1 == 2 * n + 3);   // odd half: only eR
    }
    {
      f32x16 vb[2];
      projHalf(bv, vb, area2, afB);
      transpHalf(vb, vtile, false, false);
    }
    __syncthreads();
    cgemm(macc);
  }
  __syncthreads();                   // last C-GEMM + last weight reads done

  // ---------------- M^T -> m_l (bf16, scaled) ----------------
  const float scale = 0.08838834764831845f;   // 1/sqrt(128)
  #pragma unroll
  for (int t = 0; t < 2; ++t) {
    #pragma unroll
    for (int reg = 0; reg < 16; ++reg) {
      int row = (reg & 3) + 8 * (reg >> 2) + 4 * hl;
      m_l[(rg * 32 + row) * LDW + dh * 64 + t * 32 + c] = f2bf(macc[t][reg] * scale);
    }
  }
  __syncthreads();

  // ---------------- O = Q * M ----------------
  f32x16 oacc[4];
  #pragma unroll
  for (int nt = 0; nt < 4; ++nt)
    #pragma unroll
    for (int i = 0; i < 16; ++i) oacc[nt][i] = 0.f;

  #pragma unroll
  for (int kst = 0; kst < 8; ++kst) {
    #pragma unroll
    for (int nt = 0; nt < 4; ++nt) {
      bf16x8 bb = *(const bf16x8*)(m_l + (nt * 32 + c) * LDW + kst * 16 + hl * 8);
      oacc[nt] = __builtin_amdgcn_mfma_f32_32x32x16_bf16(qf[kst], bb, oacc[nt], 0, 0, 0);
    }
  }

  // epilogue: per-wave LDS patch (32x36 f32) -> coalesced float4 stores
  float* patch = opat + wv * (32 * 36);
  float* outb  = out + ((size_t)r0 + wv * 32) * 128;
  #pragma unroll
  for (int nt = 0; nt < 4; ++nt) {
    #pragma unroll
    for (int reg = 0; reg < 16; ++reg) {
      int row = (reg & 3) + 8 * (reg >> 2) + 4 * hl;
      patch[row * 36 + c] = oacc[nt][reg];
    }
    #pragma unroll
    for (int p = 0; p < 4; ++p) {
      int row = p * 8 + (lane >> 3);
      float4 vv = *(const float4*)(patch + row * 36 + (lane & 7) * 4);
      *(float4*)(outb + (size_t)row * 128 + nt * 32 + (lane & 7) * 4) = vv;
    }
  }
}

// ---------------------------------------------------------------------------
extern "C" void kernel_launch(void* const* d_in, const int* in_sizes, int n_in,
                              void* d_out, int out_size, void* d_ws, size_t ws_size,
                              hipStream_t stream) {
  const float* x  = (const float*)d_in[0];
  const float* Wq = (const float*)d_in[1];
  const float* bq = (const float*)d_in[2];
  const float* Wk = (const float*)d_in[3];
  const float* bk = (const float*)d_in[4];
  const float* Wv = (const float*)d_in[5];
  const float* bv = (const float*)d_in[6];
  float* out = (float*)d_out;

  fused_kernel<<<256, 512, 0, stream>>>(x, Wq, bq, Wk, bk, Wv, bv, out);
}

// Round 8
// 119.150 us; speedup vs baseline: 1.1493x; 1.1493x over previous
//
#include <hip/hip_runtime.h>
#include <stdint.h>

// BlockAttention: B=8, S=8192, D=H=128, BLOCK=256, WINDOW=256 (halo 255, W=766)
// No softmax => out_blk = Q_blk @ (scale * M_n),  M_n = K_win^T V_win.
// Half-block decomposition:
//   M_n^T = sum_{j=2n-2}^{2n+3} Chalf_j^T - v_a(x)k_a - v_z(x)k_z
//   Chalf_j^T[h][d] = sum over half j's 128 keys of v[h]*k[d]  (f32)
//   a=(n-1)*256 (col 0 of even half 2n-2), z=(n+1)*256+255 (col 127 of odd
//   half 2n+3).
// kv_kernel: 512 blocks x 256 thr (2 blocks/CU: 69.6 KB LDS) -- per half j:
//   Q proj -> qb, K/V proj, Chalf GEMM -> Cpart + edge rows. 8 phases, every
//   phase pairs a memory op with a GEMM; x read once; no dead tensors.
// attn_kernel: 256 blocks x 512 thr: M^T = sum(6 halves, coalesced f32)
//   - rank-1 edges; O = Q * M. XCD swizzle for C-half L2 reuse.

#define B_ 8
#define S_ 8192
#define LDW 136   // padded leading dim (shorts) for 128-wide tiles

using bf16x8 = __attribute__((ext_vector_type(8))) short;   // 8 bf16 = 4 VGPRs
using s16x4  = __attribute__((ext_vector_type(4))) short;
using f32x16 = __attribute__((ext_vector_type(16))) float;

__device__ __forceinline__ short f2bf(float f) {
  union { float f; uint32_t u; } v; v.f = f;
  uint32_t r = v.u + 0x7fffu + ((v.u >> 16) & 1u);   // RNE
  return (short)(r >> 16);
}
__device__ __forceinline__ float bf2f(short s) {
  union { uint32_t u; float f; } v; v.u = ((uint32_t)(uint16_t)s) << 16;
  return v.f;
}

// ---------------------------------------------------------------------------
// kv_kernel: 512 blocks (b, half j) x 256 threads (4 waves), 128 rows each.
// LDS: area A + area B, each [128][LDW] bf16 = 34,816 B; total 69,632 B.
// Phase plan (8 barriers):
//  P1 stage Wq->A          | P2 Q GEMM(A)
//  P3 Q^T->B, stage Wk->A  | P4 qb<-B drain, K GEMM(A)
//  P5 K^T->B, stage Wv->A  | P6 V GEMM(A)
//  P7 V^T->A               | P8 C GEMM(A,B), edges, Cpart store
// ---------------------------------------------------------------------------
__global__ __launch_bounds__(256) void kv_kernel(
    const float* __restrict__ x,
    const float* __restrict__ Wq, const float* __restrict__ bq,
    const float* __restrict__ Wk, const float* __restrict__ bk,
    const float* __restrict__ Wv, const float* __restrict__ bv,
    short* __restrict__ qb, float* __restrict__ Cpart,
    short* __restrict__ kedge, short* __restrict__ vedge)
{
  __shared__ __align__(16) short areaA[128 * LDW];   // 34,816 B
  __shared__ __align__(16) short areaB[128 * LDW];   // 34,816 B

  const int tid  = threadIdx.x;
  const int lane = tid & 63;
  const int wv   = tid >> 6;        // 0..3
  const int c    = lane & 31;
  const int hl   = lane >> 5;
  const int r0   = blockIdx.x * 128;
  const int b    = r0 >> 13;
  const int j    = (r0 & (S_ - 1)) >> 7;   // half index 0..63

  // A fragments from x: A[m=c][k=16*kst+8*hl+jj], rows r0 + wv*32 + c
  // (shared by Q, K, V projections -- x read exactly once)
  bf16x8 afrag[8];
  {
    const float* xrow = x + (size_t)(r0 + wv * 32 + c) * 128 + hl * 8;
    #pragma unroll
    for (int kst = 0; kst < 8; ++kst) {
      const float4* p = (const float4*)(xrow + kst * 16);
      float4 f0 = p[0], f1 = p[1];
      bf16x8 a;
      a[0] = f2bf(f0.x); a[1] = f2bf(f0.y); a[2] = f2bf(f0.z); a[3] = f2bf(f0.w);
      a[4] = f2bf(f1.x); a[5] = f2bf(f1.y); a[6] = f2bf(f1.z); a[7] = f2bf(f1.w);
      afrag[kst] = a;
    }
  }

  auto stageW = [&](const float* W, short* wl) {   // 128x128 f32 -> bf16
    #pragma unroll
    for (int it = 0; it < 16; ++it) {
      int l  = it * 256 + tid;
      int nn = l >> 5;
      int k4 = (l & 31) << 2;
      const float4 f = *(const float4*)(W + nn * 128 + k4);
      s16x4 o;
      o[0] = f2bf(f.x); o[1] = f2bf(f.y); o[2] = f2bf(f.z); o[3] = f2bf(f.w);
      *(s16x4*)(wl + nn * LDW + k4) = o;
    }
  };

  auto gemm = [&](const float* bias, f32x16* acc, const short* wl) {
    #pragma unroll
    for (int nt = 0; nt < 4; ++nt) {
      float bvv = bias[nt * 32 + c];
      #pragma unroll
      for (int i = 0; i < 16; ++i) acc[nt][i] = bvv;
    }
    #pragma unroll
    for (int kst = 0; kst < 8; ++kst) {
      #pragma unroll
      for (int nt = 0; nt < 4; ++nt) {
        bf16x8 bb = *(const bf16x8*)(wl + (nt * 32 + c) * LDW + kst * 16 + hl * 8);
        acc[nt] = __builtin_amdgcn_mfma_f32_32x32x16_bf16(afrag[kst], bb, acc[nt], 0, 0, 0);
      }
    }
  };

  // C-tile layout: col=lane&31, row=(reg&3)+8*(reg>>2)+4*hl
  auto writeTransposedLDS = [&](f32x16* acc, short* wl) {   // wl[d][s], s 0..127
    #pragma unroll
    for (int nt = 0; nt < 4; ++nt) {
      int d = nt * 32 + c;
      #pragma unroll
      for (int g = 0; g < 4; ++g) {
        #pragma unroll
        for (int p = 0; p < 2; ++p) {
          int reg = g * 4 + p * 2;
          int sl  = wv * 32 + g * 8 + hl * 4 + p * 2;   // 0..127
          uint32_t pk = (uint32_t)(uint16_t)f2bf(acc[nt][reg]) |
                        ((uint32_t)(uint16_t)f2bf(acc[nt][reg + 1]) << 16);
          *(uint32_t*)(wl + d * LDW + sl) = pk;
        }
      }
    }
  };

  // ---- P1: stage Wq -> A ----
  stageW(Wq, areaA);
  __syncthreads();

  // ---- P2: Q GEMM ----
  f32x16 qacc[4];
  gemm(bq, qacc, areaA);
  __syncthreads();                   // Wq reads done

  // ---- P3: Q^T -> B [s][d]; stage Wk -> A ----
  #pragma unroll
  for (int nt = 0; nt < 4; ++nt) {
    #pragma unroll
    for (int reg = 0; reg < 16; ++reg) {
      int row = (reg & 3) + 8 * (reg >> 2) + 4 * hl;
      areaB[(wv * 32 + row) * LDW + nt * 32 + c] = f2bf(qacc[nt][reg]);
    }
  }
  stageW(Wk, areaA);
  __syncthreads();

  // ---- P4: qb <- B drain; K GEMM(A) ----
  #pragma unroll
  for (int it = 0; it < 8; ++it) {
    int l  = it * 256 + tid;
    int s  = l >> 4;
    int d8 = (l & 15) << 3;
    bf16x8 vvv = *(const bf16x8*)(areaB + s * LDW + d8);
    *(bf16x8*)(qb + (size_t)(r0 + s) * 128 + d8) = vvv;
  }
  f32x16 kacc[4];
  gemm(bk, kacc, areaA);
  __syncthreads();                   // B drain reads + Wk reads done

  // ---- P5: K^T -> B; stage Wv -> A ----
  writeTransposedLDS(kacc, areaB);
  stageW(Wv, areaA);
  __syncthreads();

  // ---- P6: V GEMM(A) ----
  f32x16 vacc[4];
  gemm(bv, vacc, areaA);
  __syncthreads();                   // Wv reads done

  // ---- P7: V^T -> A ----
  writeTransposedLDS(vacc, areaA);
  __syncthreads();

  // ---- P8: C GEMM + edges + Cpart ----
  {
    f32x16 cacc[4];
    #pragma unroll
    for (int nt = 0; nt < 4; ++nt)
      #pragma unroll
      for (int i = 0; i < 16; ++i) cacc[nt][i] = 0.f;

    #pragma unroll
    for (int kst = 0; kst < 8; ++kst) {
      bf16x8 a = *(const bf16x8*)(areaA + (wv * 32 + c) * LDW + kst * 16 + hl * 8);
      #pragma unroll
      for (int nt = 0; nt < 4; ++nt) {
        bf16x8 bb = *(const bf16x8*)(areaB + (nt * 32 + c) * LDW + kst * 16 + hl * 8);
        cacc[nt] = __builtin_amdgcn_mfma_f32_32x32x16_bf16(a, bb, cacc[nt], 0, 0, 0);
      }
    }

    // edge rows: even half -> col 0 is key with s%256==0 (slot 0 of block j/2);
    //            odd half  -> col 127 is key with s%256==255 (slot 1).
    {
      const int slot = j & 1;
      const int col  = slot ? 127 : 0;
      size_t eo = ((size_t)(b * 32 + (j >> 1))) * 256 + slot * 128;
      if (tid < 128)      kedge[eo + tid]         = areaB[tid * LDW + col];
      else                vedge[eo + (tid - 128)] = areaA[(tid - 128) * LDW + col];
    }

    float* Cp = Cpart + ((size_t)(b * 64 + j)) * 16384;   // [h][d] row-major
    #pragma unroll
    for (int nt = 0; nt < 4; ++nt) {
      #pragma unroll
      for (int reg = 0; reg < 16; ++reg) {
        int row = (reg & 3) + 8 * (reg >> 2) + 4 * hl;
        Cp[(wv * 32 + row) * 128 + nt * 32 + c] = cacc[nt][reg];
      }
    }
  }
}

// ---------------------------------------------------------------------------
// attn_kernel: 256 blocks (b,n) x 512 threads (8 waves). XCD-swizzled.
// Phase A: M^T[h][d] = scale*(sum 6 C-halves - v_a[h]k_a[d] - v_z[h]k_z[d]),
//   thread owns h = i4*16 + (tid>>5), d = (tid&31)*4..+3 (coalesced float4).
// Phase B: O = Q * M, qf straight from qb. One barrier total.
// LDS: m_l 34,816 + opat 36,864 = 71,680 B.
// ---------------------------------------------------------------------------
__global__ __launch_bounds__(512) void attn_kernel(
    const short* __restrict__ qb, const float* __restrict__ Cpart,
    const short* __restrict__ kedge, const short* __restrict__ vedge,
    float* __restrict__ out)
{
  __shared__ __align__(16) short m_l[128 * LDW];      // 34.8 KB
  __shared__ __align__(16) float opat[8 * 32 * 36];   // 36.9 KB

  const int tid  = threadIdx.x;
  const int lane = tid & 63;
  const int wv   = tid >> 6;
  const int c    = lane & 31;
  const int hl   = lane >> 5;
  // bijective XCD swizzle (256 % 8 == 0): adjacent n cluster on one XCD,
  // so the 4-of-6 shared C-halves between neighbors are L2 hits.
  const int wg   = ((int)blockIdx.x & 7) * 32 + ((int)blockIdx.x >> 3);
  const int r0   = wg * 256;
  const int b    = r0 >> 13;
  const int n    = (r0 & (S_ - 1)) >> 8;

  // ---- phase A ----
  float m[32];
  #pragma unroll
  for (int i = 0; i < 32; ++i) m[i] = 0.f;

  const float* Cb0 = Cpart + (size_t)b * 64 * 16384;
  #pragma unroll
  for (int e = 0; e < 6; ++e) {
    int hj = 2 * n - 2 + e;
    if (hj < 0 || hj >= 64) continue;        // wave-uniform branch
    const float4* Cp = (const float4*)(Cb0 + (size_t)hj * 16384);
    #pragma unroll
    for (int i4 = 0; i4 < 8; ++i4) {
      float4 f = Cp[i4 * 512 + tid];
      m[i4 * 4 + 0] += f.x; m[i4 * 4 + 1] += f.y;
      m[i4 * 4 + 2] += f.z; m[i4 * 4 + 3] += f.w;
    }
  }

  const int d0 = (tid & 31) << 2;
  if (n > 0) {   // subtract key a = (n-1)*256  (slot 0 of block n-1)
    const short* ke = kedge + ((size_t)(b * 32 + n - 1)) * 256;
    const short* ve = vedge + ((size_t)(b * 32 + n - 1)) * 256;
    float k0 = bf2f(ke[d0]),     k1 = bf2f(ke[d0 + 1]);
    float k2 = bf2f(ke[d0 + 2]), k3 = bf2f(ke[d0 + 3]);
    #pragma unroll
    for (int i4 = 0; i4 < 8; ++i4) {
      float vs = bf2f(ve[i4 * 16 + (tid >> 5)]);
      m[i4 * 4 + 0] -= vs * k0; m[i4 * 4 + 1] -= vs * k1;
      m[i4 * 4 + 2] -= vs * k2; m[i4 * 4 + 3] -= vs * k3;
    }
  }
  if (n < 31) {  // subtract key z = (n+1)*256+255  (slot 1 of block n+1)
    const short* ke = kedge + ((size_t)(b * 32 + n + 1)) * 256 + 128;
    const short* ve = vedge + ((size_t)(b * 32 + n + 1)) * 256 + 128;
    float k0 = bf2f(ke[d0]),     k1 = bf2f(ke[d0 + 1]);
    float k2 = bf2f(ke[d0 + 2]), k3 = bf2f(ke[d0 + 3]);
    #pragma unroll
    for (int i4 = 0; i4 < 8; ++i4) {
      float vs = bf2f(ve[i4 * 16 + (tid >> 5)]);
      m[i4 * 4 + 0] -= vs * k0; m[i4 * 4 + 1] -= vs * k1;
      m[i4 * 4 + 2] -= vs * k2; m[i4 * 4 + 3] -= vs * k3;
    }
  }

  const float scale = 0.08838834764831845f;   // 1/sqrt(128)
  #pragma unroll
  for (int i4 = 0; i4 < 8; ++i4) {
    int h = i4 * 16 + (tid >> 5);
    s16x4 o;
    o[0] = f2bf(m[i4 * 4 + 0] * scale); o[1] = f2bf(m[i4 * 4 + 1] * scale);
    o[2] = f2bf(m[i4 * 4 + 2] * scale); o[3] = f2bf(m[i4 * 4 + 3] * scale);
    *(s16x4*)(m_l + h * LDW + d0) = o;
  }

  // Q A-frags from qb (global; issued before the barrier to hide latency)
  bf16x8 qf[8];
  {
    const short* q0p = qb + (size_t)(r0 + wv * 32 + c) * 128 + hl * 8;
    #pragma unroll
    for (int kst = 0; kst < 8; ++kst) qf[kst] = *(const bf16x8*)(q0p + kst * 16);
  }
  __syncthreads();

  // ---- phase B: O = Q * M; wave wv owns 32 q-rows [r0+32wv, +32) ----
  f32x16 oacc[4];
  #pragma unroll
  for (int nt = 0; nt < 4; ++nt)
    #pragma unroll
    for (int i = 0; i < 16; ++i) oacc[nt][i] = 0.f;

  #pragma unroll
  for (int kst = 0; kst < 8; ++kst) {
    #pragma unroll
    for (int nt = 0; nt < 4; ++nt) {
      bf16x8 bb = *(const bf16x8*)(m_l + (nt * 32 + c) * LDW + kst * 16 + hl * 8);
      oacc[nt] = __builtin_amdgcn_mfma_f32_32x32x16_bf16(qf[kst], bb, oacc[nt], 0, 0, 0);
    }
  }

  // epilogue: per-wave LDS patch (32x36 f32) -> coalesced float4 stores
  float* patch = opat + wv * (32 * 36);
  float* outb  = out + ((size_t)r0 + wv * 32) * 128;
  #pragma unroll
  for (int nt = 0; nt < 4; ++nt) {
    #pragma unroll
    for (int reg = 0; reg < 16; ++reg) {
      int row = (reg & 3) + 8 * (reg >> 2) + 4 * hl;
      patch[row * 36 + c] = oacc[nt][reg];
    }
    #pragma unroll
    for (int p = 0; p < 4; ++p) {
      int row = p * 8 + (lane >> 3);
      float4 vv = *(const float4*)(patch + row * 36 + (lane & 7) * 4);
      *(float4*)(outb + (size_t)row * 128 + nt * 32 + (lane & 7) * 4) = vv;
    }
  }
}

// ---------------------------------------------------------------------------
extern "C" void kernel_launch(void* const* d_in, const int* in_sizes, int n_in,
                              void* d_out, int out_size, void* d_ws, size_t ws_size,
                              hipStream_t stream) {
  const float* x  = (const float*)d_in[0];
  const float* Wq = (const float*)d_in[1];
  const float* bq = (const float*)d_in[2];
  const float* Wk = (const float*)d_in[3];
  const float* bk = (const float*)d_in[4];
  const float* Wv = (const float*)d_in[5];
  const float* bv = (const float*)d_in[6];
  float* out = (float*)d_out;

  float* Cpart = (float*)d_ws;                          // 8*64*128*128 f32 = 33.6MB
  short* kedge = (short*)(Cpart + (size_t)8 * 64 * 16384);
  short* vedge = kedge + (size_t)8 * 32 * 256;
  short* qb    = vedge + (size_t)8 * 32 * 256;          // 16.8MB bf16 [b][s][d]

  kv_kernel<<<512, 256, 0, stream>>>(x, Wq, bq, Wk, bk, Wv, bv,
                                     qb, Cpart, kedge, vedge);
  attn_kernel<<<256, 512, 0, stream>>>(qb, Cpart, kedge, vedge, out);
}

// Round 9
// 118.041 us; speedup vs baseline: 1.1601x; 1.0094x over previous
//
#include <hip/hip_runtime.h>
#include <stdint.h>

// BlockAttention: B=8, S=8192, D=H=128, BLOCK=256, WINDOW=256 (halo 255, W=766)
// No softmax => out_blk = Q_blk @ (scale*M_n) = x_blk @ N_n + 1 (x) bqM_n
//   where M_n^T = C_{n-1}^T + C_n^T + C_{n+1}^T - v_a(x)k_a - v_z(x)k_z,
//         N_n = Wq^T (scale*M_n)   (128x128, computed per block in-LDS),
//         bqM_n[h] = sum_f bq[f]*(scale*M_n)[f][h]  (rank-1 bias term).
// Q IS NEVER MATERIALIZED (no qb tensor, no Q GEMM in kv).
// kv_kernel:  256 blocks (b,n) x 512 thr, 4 phases: stage Wk+Wv | K+V GEMM |
//             both transposes | C-GEMM -> Cpart + edge rows.
// attn_kernel: 256 blocks x 512 thr, 2 barriers: phase A (3 C blocks +
//             rank-1 edges + bqM reduce) -> m_l; N-GEMM -> n_l; O = x*N + bias.
// Both grids share one bijective XCD swizzle so C_n write/read are L2-local.

#define B_ 8
#define S_ 8192
#define LDW 136   // padded leading dim (shorts) for 128-wide tiles
#define LDT 264   // padded leading dim (shorts) for 256-wide K^T/V^T tiles

using bf16x8 = __attribute__((ext_vector_type(8))) short;   // 8 bf16 = 4 VGPRs
using s16x4  = __attribute__((ext_vector_type(4))) short;
using f32x16 = __attribute__((ext_vector_type(16))) float;

__device__ __forceinline__ short f2bf(float f) {
  union { float f; uint32_t u; } v; v.f = f;
  uint32_t r = v.u + 0x7fffu + ((v.u >> 16) & 1u);   // RNE
  return (short)(r >> 16);
}
__device__ __forceinline__ float bf2f(short s) {
  union { uint32_t u; float f; } v; v.u = ((uint32_t)(uint16_t)s) << 16;
  return v.f;
}

// ---------------------------------------------------------------------------
// kv_kernel: 256 blocks (b,n) x 512 threads (8 waves), 256 keys each.
// LDS: areaA (Wk -> K^T [128][LDT]) + areaB (Wv -> V^T), 2 x 67,584 B.
// 4 barriers total.
// ---------------------------------------------------------------------------
__global__ __launch_bounds__(512) void kv_kernel(
    const float* __restrict__ x,
    const float* __restrict__ Wk, const float* __restrict__ bk,
    const float* __restrict__ Wv, const float* __restrict__ bv,
    float* __restrict__ Cpart, short* __restrict__ kedge,
    short* __restrict__ vedge)
{
  __shared__ __align__(16) char smem[135168];
  short* areaA = (short*)smem;            // Wk stage -> K^T tile [d][s]
  short* areaB = (short*)(smem + 67584);  // Wv stage -> V^T tile [h][s]

  const int tid  = threadIdx.x;
  const int lane = tid & 63;
  const int wv   = tid >> 6;        // 0..7
  const int c    = lane & 31;
  const int hl   = lane >> 5;
  // bijective XCD swizzle (256 % 8 == 0): XCD k owns wg k*32..+32 (= batch k)
  const int wg   = ((int)blockIdx.x & 7) * 32 + ((int)blockIdx.x >> 3);
  const int r0   = wg * 256;
  const int b    = r0 >> 13;
  const int n    = (r0 & (S_ - 1)) >> 8;

  // A fragments from x: A[m=c][k=16*kst+8*hl+j], rows r0 + wv*32 + c
  bf16x8 afrag[8];
  {
    const float* xrow = x + (size_t)(r0 + wv * 32 + c) * 128 + hl * 8;
    #pragma unroll
    for (int kst = 0; kst < 8; ++kst) {
      const float4* p = (const float4*)(xrow + kst * 16);
      float4 f0 = p[0], f1 = p[1];
      bf16x8 a;
      a[0] = f2bf(f0.x); a[1] = f2bf(f0.y); a[2] = f2bf(f0.z); a[3] = f2bf(f0.w);
      a[4] = f2bf(f1.x); a[5] = f2bf(f1.y); a[6] = f2bf(f1.z); a[7] = f2bf(f1.w);
      afrag[kst] = a;
    }
  }

  auto stageW = [&](const float* W, short* wl) {   // 128x128 f32 -> bf16
    #pragma unroll
    for (int it = 0; it < 8; ++it) {
      int l  = it * 512 + tid;
      int nn = l >> 5;
      int k4 = (l & 31) << 2;
      const float4 f = *(const float4*)(W + nn * 128 + k4);
      s16x4 o;
      o[0] = f2bf(f.x); o[1] = f2bf(f.y); o[2] = f2bf(f.z); o[3] = f2bf(f.w);
      *(s16x4*)(wl + nn * LDW + k4) = o;
    }
  };

  auto gemm = [&](const float* bias, f32x16* acc, const short* wl) {
    #pragma unroll
    for (int nt = 0; nt < 4; ++nt) {
      float bvv = bias[nt * 32 + c];
      #pragma unroll
      for (int i = 0; i < 16; ++i) acc[nt][i] = bvv;
    }
    #pragma unroll
    for (int kst = 0; kst < 8; ++kst) {
      #pragma unroll
      for (int nt = 0; nt < 4; ++nt) {
        bf16x8 bb = *(const bf16x8*)(wl + (nt * 32 + c) * LDW + kst * 16 + hl * 8);
        acc[nt] = __builtin_amdgcn_mfma_f32_32x32x16_bf16(afrag[kst], bb, acc[nt], 0, 0, 0);
      }
    }
  };

  // C-tile layout: col=lane&31, row=(reg&3)+8*(reg>>2)+4*hl
  auto writeTransposedLDS = [&](f32x16* acc, short* wl) {   // wl[d][s], LDT rows
    #pragma unroll
    for (int nt = 0; nt < 4; ++nt) {
      int d = nt * 32 + c;
      #pragma unroll
      for (int g = 0; g < 4; ++g) {
        #pragma unroll
        for (int p = 0; p < 2; ++p) {
          int reg = g * 4 + p * 2;
          int sl  = wv * 32 + g * 8 + hl * 4 + p * 2;   // 0..255
          uint32_t pk = (uint32_t)(uint16_t)f2bf(acc[nt][reg]) |
                        ((uint32_t)(uint16_t)f2bf(acc[nt][reg + 1]) << 16);
          *(uint32_t*)(wl + d * LDT + sl) = pk;
        }
      }
    }
  };

  // ---- P1: stage Wk -> A, Wv -> B ----
  stageW(Wk, areaA);
  stageW(Wv, areaB);
  __syncthreads();

  // ---- P2: K GEMM(A) + V GEMM(B), one phase ----
  f32x16 kacc[4], vacc[4];
  gemm(bk, kacc, areaA);
  gemm(bv, vacc, areaB);
  __syncthreads();                   // weight reads done

  // ---- P3: K^T -> A, V^T -> B ----
  writeTransposedLDS(kacc, areaA);
  writeTransposedLDS(vacc, areaB);
  __syncthreads();

  // ---- P4: C-GEMM + edges + Cpart ----
  {
    const int ht = wv >> 1;          // 4 x 32 h-rows
    const int dh = wv & 1;           // 2 x 64 d-cols
    f32x16 cacc[2];
    #pragma unroll
    for (int t = 0; t < 2; ++t)
      #pragma unroll
      for (int i = 0; i < 16; ++i) cacc[t][i] = 0.f;

    #pragma unroll
    for (int kst = 0; kst < 16; ++kst) {
      bf16x8 a  = *(const bf16x8*)(areaB + (ht * 32 + c) * LDT + kst * 16 + hl * 8);
      bf16x8 b0 = *(const bf16x8*)(areaA + (dh * 64 + c) * LDT + kst * 16 + hl * 8);
      bf16x8 b1 = *(const bf16x8*)(areaA + (dh * 64 + 32 + c) * LDT + kst * 16 + hl * 8);
      cacc[0] = __builtin_amdgcn_mfma_f32_32x32x16_bf16(a, b0, cacc[0], 0, 0, 0);
      cacc[1] = __builtin_amdgcn_mfma_f32_32x32x16_bf16(a, b1, cacc[1], 0, 0, 0);
    }

    // edge rows: slot0 = key n*256 (tile col 0), slot1 = key n*256+255 (col 255)
    {
      size_t eo = ((size_t)(b * 32 + n)) * 256;
      if (tid < 128)      kedge[eo + tid]               = areaA[tid * LDT + 0];
      else if (tid < 256) kedge[eo + 128 + (tid - 128)] = areaA[(tid - 128) * LDT + 255];
      else if (tid < 384) vedge[eo + (tid - 256)]       = areaB[(tid - 256) * LDT + 0];
      else                vedge[eo + 128 + (tid - 384)] = areaB[(tid - 384) * LDT + 255];
    }

    float* Cp = Cpart + ((size_t)(b * 32 + n)) * 16384;   // [h][d] row-major
    #pragma unroll
    for (int t = 0; t < 2; ++t) {
      #pragma unroll
      for (int reg = 0; reg < 16; ++reg) {
        int row = (reg & 3) + 8 * (reg >> 2) + 4 * hl;
        Cp[(ht * 32 + row) * 128 + dh * 64 + t * 32 + c] = cacc[t][reg];
      }
    }
  }
}

// ---------------------------------------------------------------------------
// attn_kernel: 256 blocks (b,n) x 512 threads (8 waves). Q-free.
// Phase A: m[h][f] = scale*(sum 3 C - v_a k_a - v_z k_z); bqM shuffle-reduce;
//          m_l bf16.  (thread owns h = i4*16+(tid>>5), f = (tid&31)*4..+3)
// N-GEMM:  N2[h][d] = sum_f m_l[h][f] * Wq[f][d]   (B-op = wqT[d][f] rows d)
// O-GEMM:  O[s][h]  = sum_d x[s][d] * n_l[h][d] + bqM[h]
// LDS: wqT 34,816 | m_l 34,816 | n_l 34,816 | bqM 512; opat aliases [0,36864).
// ---------------------------------------------------------------------------
__global__ __launch_bounds__(512) void attn_kernel(
    const float* __restrict__ x,
    const float* __restrict__ Wq, const float* __restrict__ bq,
    const float* __restrict__ Cpart,
    const short* __restrict__ kedge, const short* __restrict__ vedge,
    float* __restrict__ out)
{
  __shared__ __align__(16) char smem[104960];
  short* wqT   = (short*)smem;             // [d][f] transposed Wq, bf16
  short* m_l   = (short*)(smem + 34816);   // [h][f] scale*M^T, bf16
  short* n_l   = (short*)(smem + 69632);   // [h][d] N2, bf16
  float* bqM_l = (float*)(smem + 104448);  // [128]
  float* opat  = (float*)smem;             // epilogue patches (after barrier 2)

  const int tid  = threadIdx.x;
  const int lane = tid & 63;
  const int wv   = tid >> 6;
  const int c    = lane & 31;
  const int hl   = lane >> 5;
  const int wg   = ((int)blockIdx.x & 7) * 32 + ((int)blockIdx.x >> 3);
  const int r0   = wg * 256;
  const int b    = r0 >> 13;
  const int n    = (r0 & (S_ - 1)) >> 8;

  // x A-frags (needed only in O-GEMM; issued first to hide latency; L3-warm)
  bf16x8 afrag[8];
  {
    const float* xrow = x + (size_t)(r0 + wv * 32 + c) * 128 + hl * 8;
    #pragma unroll
    for (int kst = 0; kst < 8; ++kst) {
      const float4* p = (const float4*)(xrow + kst * 16);
      float4 f0 = p[0], f1 = p[1];
      bf16x8 a;
      a[0] = f2bf(f0.x); a[1] = f2bf(f0.y); a[2] = f2bf(f0.z); a[3] = f2bf(f0.w);
      a[4] = f2bf(f1.x); a[5] = f2bf(f1.y); a[6] = f2bf(f1.z); a[7] = f2bf(f1.w);
      afrag[kst] = a;
    }
  }

  // stage Wq TRANSPOSED: read Wq[f][d4..+3] coalesced, write wqT[d][f]
  #pragma unroll
  for (int it = 0; it < 8; ++it) {
    int l  = it * 512 + tid;
    int f  = l >> 5;
    int d4 = (l & 31) << 2;
    const float4 w = *(const float4*)(Wq + f * 128 + d4);
    wqT[(d4 + 0) * LDW + f] = f2bf(w.x);
    wqT[(d4 + 1) * LDW + f] = f2bf(w.y);
    wqT[(d4 + 2) * LDW + f] = f2bf(w.z);
    wqT[(d4 + 3) * LDW + f] = f2bf(w.w);
  }

  // ---- phase A ----
  float m[32];
  #pragma unroll
  for (int i = 0; i < 32; ++i) m[i] = 0.f;

  const float* Cb0 = Cpart + (size_t)b * 32 * 16384;
  #pragma unroll
  for (int e = 0; e < 3; ++e) {
    int nn = n - 1 + e;
    if (nn < 0 || nn > 31) continue;          // wave-uniform branch
    const float4* Cp = (const float4*)(Cb0 + (size_t)nn * 16384);
    #pragma unroll
    for (int i4 = 0; i4 < 8; ++i4) {
      float4 f = Cp[i4 * 512 + tid];
      m[i4 * 4 + 0] += f.x; m[i4 * 4 + 1] += f.y;
      m[i4 * 4 + 2] += f.z; m[i4 * 4 + 3] += f.w;
    }
  }

  const int d0 = (tid & 31) << 2;
  if (n > 0) {   // subtract key a = (n-1)*256  (slot 0 of block n-1)
    const short* ke = kedge + ((size_t)(b * 32 + n - 1)) * 256;
    const short* ve = vedge + ((size_t)(b * 32 + n - 1)) * 256;
    float k0 = bf2f(ke[d0]),     k1 = bf2f(ke[d0 + 1]);
    float k2 = bf2f(ke[d0 + 2]), k3 = bf2f(ke[d0 + 3]);
    #pragma unroll
    for (int i4 = 0; i4 < 8; ++i4) {
      float vs = bf2f(ve[i4 * 16 + (tid >> 5)]);
      m[i4 * 4 + 0] -= vs * k0; m[i4 * 4 + 1] -= vs * k1;
      m[i4 * 4 + 2] -= vs * k2; m[i4 * 4 + 3] -= vs * k3;
    }
  }
  if (n < 31) {  // subtract key z = (n+1)*256+255  (slot 1 of block n+1)
    const short* ke = kedge + ((size_t)(b * 32 + n + 1)) * 256 + 128;
    const short* ve = vedge + ((size_t)(b * 32 + n + 1)) * 256 + 128;
    float k0 = bf2f(ke[d0]),     k1 = bf2f(ke[d0 + 1]);
    float k2 = bf2f(ke[d0 + 2]), k3 = bf2f(ke[d0 + 3]);
    #pragma unroll
    for (int i4 = 0; i4 < 8; ++i4) {
      float vs = bf2f(ve[i4 * 16 + (tid >> 5)]);
      m[i4 * 4 + 0] -= vs * k0; m[i4 * 4 + 1] -= vs * k1;
      m[i4 * 4 + 2] -= vs * k2; m[i4 * 4 + 3] -= vs * k3;
    }
  }

  const float scale = 0.08838834764831845f;   // 1/sqrt(128)
  // m_l write + bqM partials (over f = d0..d0+3 for 8 h's each)
  float4 bqv = *(const float4*)(bq + d0);
  float bp[8];
  #pragma unroll
  for (int i4 = 0; i4 < 8; ++i4) {
    int h = i4 * 16 + (tid >> 5);
    float m0 = m[i4 * 4 + 0] * scale, m1 = m[i4 * 4 + 1] * scale;
    float m2 = m[i4 * 4 + 2] * scale, m3 = m[i4 * 4 + 3] * scale;
    s16x4 o;
    o[0] = f2bf(m0); o[1] = f2bf(m1); o[2] = f2bf(m2); o[3] = f2bf(m3);
    *(s16x4*)(m_l + h * LDW + d0) = o;
    bp[i4] = m0 * bqv.x + m1 * bqv.y + m2 * bqv.z + m3 * bqv.w;
  }
  // reduce bqM over the 32 threads sharing each h (low 5 bits of tid)
  #pragma unroll
  for (int mask = 1; mask <= 16; mask <<= 1) {
    #pragma unroll
    for (int i4 = 0; i4 < 8; ++i4) bp[i4] += __shfl_xor(bp[i4], mask);
  }
  if ((tid & 31) == 0) {
    #pragma unroll
    for (int i4 = 0; i4 < 8; ++i4) bqM_l[i4 * 16 + (tid >> 5)] = bp[i4];
  }
  __syncthreads();   // barrier 1: wqT, m_l, bqM_l ready

  // ---- N-GEMM: N2[h][d] = sum_f m_l[h][f] * wqT[d][f] ----
  {
    const int ht2 = wv >> 1;        // 4 x 32 h-rows
    const int dc  = (wv & 1) * 64;  // 2 x 64 d-cols
    f32x16 nacc[2];
    #pragma unroll
    for (int t = 0; t < 2; ++t)
      #pragma unroll
      for (int i = 0; i < 16; ++i) nacc[t][i] = 0.f;

    #pragma unroll
    for (int kst = 0; kst < 8; ++kst) {
      bf16x8 a = *(const bf16x8*)(m_l + (ht2 * 32 + c) * LDW + kst * 16 + hl * 8);
      #pragma unroll
      for (int t = 0; t < 2; ++t) {
        bf16x8 bb = *(const bf16x8*)(wqT + (dc + t * 32 + c) * LDW + kst * 16 + hl * 8);
        nacc[t] = __builtin_amdgcn_mfma_f32_32x32x16_bf16(a, bb, nacc[t], 0, 0, 0);
      }
    }
    // D[m=h][n=d]: col=lane&31=d-within, row=(reg&3)+8*(reg>>2)+4*hl
    #pragma unroll
    for (int t = 0; t < 2; ++t) {
      #pragma unroll
      for (int reg = 0; reg < 16; ++reg) {
        int row = (reg & 3) + 8 * (reg >> 2) + 4 * hl;
        n_l[(ht2 * 32 + row) * LDW + dc + t * 32 + c] = f2bf(nacc[t][reg]);
      }
    }
  }
  __syncthreads();   // barrier 2: n_l ready; wqT/m_l dead (opat may alias)

  // ---- O-GEMM: O[s][h] = sum_d x[s][d] * n_l[h][d] + bqM[h] ----
  f32x16 oacc[4];
  #pragma unroll
  for (int nt = 0; nt < 4; ++nt)
    #pragma unroll
    for (int i = 0; i < 16; ++i) oacc[nt][i] = 0.f;

  #pragma unroll
  for (int kst = 0; kst < 8; ++kst) {
    #pragma unroll
    for (int nt = 0; nt < 4; ++nt) {
      bf16x8 bb = *(const bf16x8*)(n_l + (nt * 32 + c) * LDW + kst * 16 + hl * 8);
      oacc[nt] = __builtin_amdgcn_mfma_f32_32x32x16_bf16(afrag[kst], bb, oacc[nt], 0, 0, 0);
    }
  }

  // epilogue: + bias, per-wave LDS patch (32x36 f32) -> coalesced float4 stores
  float* patch = opat + wv * (32 * 36);
  float* outb  = out + ((size_t)r0 + wv * 32) * 128;
  #pragma unroll
  for (int nt = 0; nt < 4; ++nt) {
    float bias = bqM_l[nt * 32 + c];
    #pragma unroll
    for (int reg = 0; reg < 16; ++reg) {
      int row = (reg & 3) + 8 * (reg >> 2) + 4 * hl;
      patch[row * 36 + c] = oacc[nt][reg] + bias;
    }
    #pragma unroll
    for (int p = 0; p < 4; ++p) {
      int row = p * 8 + (lane >> 3);
      float4 vv = *(const float4*)(patch + row * 36 + (lane & 7) * 4);
      *(float4*)(outb + (size_t)row * 128 + nt * 32 + (lane & 7) * 4) = vv;
    }
  }
}

// ---------------------------------------------------------------------------
extern "C" void kernel_launch(void* const* d_in, const int* in_sizes, int n_in,
                              void* d_out, int out_size, void* d_ws, size_t ws_size,
                              hipStream_t stream) {
  const float* x  = (const float*)d_in[0];
  const float* Wq = (const float*)d_in[1];
  const float* bq = (const float*)d_in[2];
  const float* Wk = (const float*)d_in[3];
  const float* bk = (const float*)d_in[4];
  const float* Wv = (const float*)d_in[5];
  const float* bv = (const float*)d_in[6];
  float* out = (float*)d_out;

  float* Cpart = (float*)d_ws;                          // 8*32*128*128 f32 = 16.8MB
  short* kedge = (short*)(Cpart + (size_t)8 * 32 * 16384);
  short* vedge = kedge + (size_t)8 * 32 * 256;

  kv_kernel<<<256, 512, 0, stream>>>(x, Wk, bk, Wv, bv, Cpart, kedge, vedge);
  attn_kernel<<<256, 512, 0, stream>>>(x, Wq, bq, Cpart, kedge, vedge, out);
}